// Round 8
// baseline (1574.486 us; speedup 1.0000x reference)
//
#include <hip/hip_runtime.h>
#include <stdint.h>

#define N_NODES 100000
#define N_EDGES 300000
#define D_IN 256
#define HID 1024
#define N_CLASSES 64
#define NSCAN ((N_NODES + 1023) / 1024)   // 98 scan blocks

typedef __bf16 bf16x8 __attribute__((ext_vector_type(8)));
typedef float f32x4 __attribute__((ext_vector_type(4)));

__device__ __forceinline__ float bf2f(unsigned short u) {
  union { unsigned int i; float f; } v; v.i = ((unsigned int)u) << 16; return v.f;
}
__device__ __forceinline__ unsigned short f2bf(float f) {
  union { float f; unsigned int i; } v; v.f = f;
  unsigned int u = v.i;
  unsigned int r = (u + 0x7FFFu + ((u >> 16) & 1u)) >> 16;  // RNE
  return (unsigned short)r;
}

// async global->LDS, 16B per lane; LDS dest wave-uniform base, 16B-aligned
__device__ __forceinline__ void async16(const void* g, void* l) {
  __builtin_amdgcn_global_load_lds(
      (const __attribute__((address_space(1))) void*)g,
      (__attribute__((address_space(3))) void*)l, 16, 0, 0);
}

// ---------------------------------------------------------------------------
// dtype probe: flags[0]=1 if float tensors are f32 (vs bf16),
//              flags[1]=1 if edge_index is int64 (vs int32).
// ---------------------------------------------------------------------------
__global__ void probe_flags(const unsigned short* __restrict__ w,
                            const unsigned int* __restrict__ e,
                            int* __restrict__ flags) {
  __shared__ int cnt;
  __shared__ unsigned int orv;
  if (threadIdx.x == 0) { cnt = 0; orv = 0u; }
  __syncthreads();
  int c = 0;
  for (int i = threadIdx.x; i < 4096; i += 256) {
    unsigned int ex = (w[i] >> 7) & 0xFFu;
    if (ex > 123u) ++c;
  }
  atomicAdd(&cnt, c);
  unsigned int o = 0;
  for (int j = threadIdx.x; j < 1000; j += 256) o |= e[2 * j + 1];
  atomicOr(&orv, o);
  __syncthreads();
  if (threadIdx.x == 0) {
    flags[0] = (cnt > 64) ? 1 : 0;
    flags[1] = (orv == 0u) ? 1 : 0;
  }
}

__global__ void cvt_edges(const unsigned int* __restrict__ ei,
                          int* __restrict__ src32, int* __restrict__ dst32,
                          const int* __restrict__ flags) {
  int i = blockIdx.x * 256 + threadIdx.x;
  if (i >= N_EDGES) return;
  if (flags[1]) {
    src32[i] = (int)ei[2 * i];
    dst32[i] = (int)ei[2 * (size_t)N_EDGES + 2 * i];
  } else {
    src32[i] = (int)ei[i];
    dst32[i] = (int)ei[N_EDGES + i];
  }
}

// LDS-tiled 64x64 transpose: coalesced read AND write.
// grid = (N/64, K/64). FB16=1 forces bf16 input (ignores flags).
template <int FB16>
__global__ void transpose_tile(const void* __restrict__ W,
                               unsigned short* __restrict__ Wt, int K, int N,
                               const int* __restrict__ flags) {
  __shared__ float t[64][65];   // +1 pad: LDS reads 2-way max (free)
  const int n0 = blockIdx.x * 64, k0 = blockIdx.y * 64;
  const int lane = threadIdx.x & 63, rg = threadIdx.x >> 6;
  const bool isf32 = FB16 ? false : (flags[0] != 0);
#pragma unroll
  for (int i = 0; i < 16; ++i) {
    int r = rg * 16 + i;
    long idx = (long)(k0 + r) * N + n0 + lane;
    t[r][lane] = isf32 ? ((const float*)W)[idx]
                       : bf2f(((const unsigned short*)W)[idx]);
  }
  __syncthreads();
#pragma unroll
  for (int i = 0; i < 16; ++i) {
    int r = rg * 16 + i;
    Wt[(long)(n0 + r) * K + k0 + lane] = f2bf(t[lane][r]);
  }
}

// all 5 biases in one launch; dst buffers are contiguous (bb1a..bbfc).
__global__ void cvt_bias_all(const void* __restrict__ b1a, const void* __restrict__ b1b,
                             const void* __restrict__ b2a, const void* __restrict__ b2b,
                             const void* __restrict__ bfc,
                             unsigned short* __restrict__ bb,
                             const int* __restrict__ flags) {
  int i = blockIdx.x * 256 + threadIdx.x;
  if (i >= 4 * HID + N_CLASSES) return;
  const void* src; int off;
  if (i < HID)          { src = b1a; off = i; }
  else if (i < 2 * HID) { src = b1b; off = i - HID; }
  else if (i < 3 * HID) { src = b2a; off = i - 2 * HID; }
  else if (i < 4 * HID) { src = b2b; off = i - 3 * HID; }
  else                  { src = bfc; off = i - 4 * HID; }
  bb[i] = flags[0] ? f2bf(((const float*)src)[off])
                   : ((const unsigned short*)src)[off];
}

// bcomb[c] = sum_j b2b[j] * Wfc[j][c] + bfc[c]   (f32 accum, bf16 out)
__global__ void bcomb_kernel(const unsigned short* __restrict__ bb2b,
                             const unsigned short* __restrict__ WfcT,
                             const unsigned short* __restrict__ bbfc,
                             unsigned short* __restrict__ bcomb) {
  int c = threadIdx.x;
  if (c >= N_CLASSES) return;
  float s = bf2f(bbfc[c]);
  for (int j = 0; j < HID; ++j)
    s += bf2f(bb2b[j]) * bf2f(WfcT[(long)c * HID + j]);
  bcomb[c] = f2bf(s);
}

// ---------------- CSR build (counting sort by dst) ----------------
__global__ void hist_deg(const int* __restrict__ dst, int* __restrict__ deg) {
  int e = blockIdx.x * 256 + threadIdx.x;
  if (e < N_EDGES) atomicAdd(&deg[dst[e]], 1);
}

// hierarchical scan, stage 1: per-block inclusive scan of 1024 deg entries.
__global__ void scan_part(const int* __restrict__ deg, int* __restrict__ rowptr,
                          int* __restrict__ bsum) {
  __shared__ int lds[1024];
  int i = blockIdx.x * 1024 + threadIdx.x;
  int v = (i < N_NODES) ? deg[i] : 0;
  lds[threadIdx.x] = v;
  __syncthreads();
  for (int off = 1; off < 1024; off <<= 1) {
    int t = (threadIdx.x >= off) ? lds[threadIdx.x - off] : 0;
    __syncthreads();
    lds[threadIdx.x] += t;
    __syncthreads();
  }
  if (i < N_NODES) rowptr[i + 1] = lds[threadIdx.x];
  if (threadIdx.x == 1023) bsum[blockIdx.x] = lds[1023];
}

// stage 2: one small block exclusive-scans the NSCAN block sums in place.
__global__ void scan_top(int* __restrict__ bsum) {
  __shared__ int lds[128];
  int v = (threadIdx.x < NSCAN) ? bsum[threadIdx.x] : 0;
  lds[threadIdx.x] = v;
  __syncthreads();
  for (int off = 1; off < 128; off <<= 1) {
    int t = (threadIdx.x >= off) ? lds[threadIdx.x - off] : 0;
    __syncthreads();
    lds[threadIdx.x] += t;
    __syncthreads();
  }
  if (threadIdx.x < NSCAN) bsum[threadIdx.x] = lds[threadIdx.x] - v;  // exclusive
}

// stage 3: add block offsets, finalize rowptr and cursor.
__global__ void scan_fix(const int* __restrict__ deg, int* __restrict__ rowptr,
                         int* __restrict__ cursor, const int* __restrict__ bsum) {
  int i = blockIdx.x * 1024 + threadIdx.x;
  if (i < N_NODES) {
    int incl = rowptr[i + 1] + bsum[blockIdx.x];
    rowptr[i + 1] = incl;
    cursor[i] = incl - deg[i];
  }
  if (i == 0) rowptr[0] = 0;
}

__global__ void fill_csr(const int* __restrict__ src, const int* __restrict__ dst,
                         int* __restrict__ cursor, int* __restrict__ csr) {
  int e = blockIdx.x * 256 + threadIdx.x;
  if (e < N_EDGES) {
    int pos = atomicAdd(&cursor[dst[e]], 1);
    csr[pos] = src[e];
  }
}

// ---- atomic-free aggregation, one wave per node ----
// layer 1: h[n] = bf16(x[n] + sum_j x[csr[j]])  (x f32 or bf16; 4 cols/lane)
// edge loop unrolled x4 (adds kept in original order -> bitwise identical).
__global__ void agg1_full(const void* __restrict__ X,
                          const int* __restrict__ rowptr,
                          const int* __restrict__ csr,
                          unsigned short* __restrict__ h,
                          const int* __restrict__ flags) {
  int node = blockIdx.x * 4 + (threadIdx.x >> 6);
  int lane = threadIdx.x & 63;
  if (node >= N_NODES) return;
  bool isf32 = flags[0] != 0;
  float acc[4];
  int e0 = rowptr[node], e1 = rowptr[node + 1];
  if (isf32) {
    const float* Xf = (const float*)X;
    float4 v = ((const float4*)(Xf + (long)node * D_IN))[lane];
    acc[0] = v.x; acc[1] = v.y; acc[2] = v.z; acc[3] = v.w;
    int j = e0;
    for (; j + 3 < e1; j += 4) {
      int s0 = csr[j], s1 = csr[j + 1], s2 = csr[j + 2], s3 = csr[j + 3];
      float4 v0 = ((const float4*)(Xf + (long)s0 * D_IN))[lane];
      float4 v1 = ((const float4*)(Xf + (long)s1 * D_IN))[lane];
      float4 v2 = ((const float4*)(Xf + (long)s2 * D_IN))[lane];
      float4 v3 = ((const float4*)(Xf + (long)s3 * D_IN))[lane];
      acc[0] += v0.x; acc[1] += v0.y; acc[2] += v0.z; acc[3] += v0.w;
      acc[0] += v1.x; acc[1] += v1.y; acc[2] += v1.z; acc[3] += v1.w;
      acc[0] += v2.x; acc[1] += v2.y; acc[2] += v2.z; acc[3] += v2.w;
      acc[0] += v3.x; acc[1] += v3.y; acc[2] += v3.z; acc[3] += v3.w;
    }
    for (; j < e1; ++j) {
      int s = csr[j];
      float4 v0 = ((const float4*)(Xf + (long)s * D_IN))[lane];
      acc[0] += v0.x; acc[1] += v0.y; acc[2] += v0.z; acc[3] += v0.w;
    }
  } else {
    const unsigned short* Xb = (const unsigned short*)X;
    ushort4 v = ((const ushort4*)(Xb + (long)node * D_IN))[lane];
    acc[0] = bf2f(v.x); acc[1] = bf2f(v.y); acc[2] = bf2f(v.z); acc[3] = bf2f(v.w);
    int j = e0;
    for (; j + 3 < e1; j += 4) {
      int s0 = csr[j], s1 = csr[j + 1], s2 = csr[j + 2], s3 = csr[j + 3];
      ushort4 v0 = ((const ushort4*)(Xb + (long)s0 * D_IN))[lane];
      ushort4 v1 = ((const ushort4*)(Xb + (long)s1 * D_IN))[lane];
      ushort4 v2 = ((const ushort4*)(Xb + (long)s2 * D_IN))[lane];
      ushort4 v3 = ((const ushort4*)(Xb + (long)s3 * D_IN))[lane];
      acc[0] += bf2f(v0.x); acc[1] += bf2f(v0.y); acc[2] += bf2f(v0.z); acc[3] += bf2f(v0.w);
      acc[0] += bf2f(v1.x); acc[1] += bf2f(v1.y); acc[2] += bf2f(v1.z); acc[3] += bf2f(v1.w);
      acc[0] += bf2f(v2.x); acc[1] += bf2f(v2.y); acc[2] += bf2f(v2.z); acc[3] += bf2f(v2.w);
      acc[0] += bf2f(v3.x); acc[1] += bf2f(v3.y); acc[2] += bf2f(v3.z); acc[3] += bf2f(v3.w);
    }
    for (; j < e1; ++j) {
      int s = csr[j];
      ushort4 v0 = ((const ushort4*)(Xb + (long)s * D_IN))[lane];
      acc[0] += bf2f(v0.x); acc[1] += bf2f(v0.y); acc[2] += bf2f(v0.z); acc[3] += bf2f(v0.w);
    }
  }
  ushort4 o;
  o.x = f2bf(acc[0]); o.y = f2bf(acc[1]); o.z = f2bf(acc[2]); o.w = f2bf(acc[3]);
  ((ushort4*)(h + (long)node * D_IN))[lane] = o;
}

// layer 2 aggregation, 128-col slice, with column rotation; edge loop
// unrolled x2 (order-preserving adds).
__global__ void agg2_rot(const unsigned short* __restrict__ Q,
                         const int* __restrict__ rowptr,
                         const int* __restrict__ csr,
                         unsigned short* __restrict__ out, long ostride, int cb) {
  int node = blockIdx.x * 4 + (threadIdx.x >> 6);
  int lane = threadIdx.x & 63;
  if (node >= N_NODES) return;
  unsigned int p = ((const unsigned int*)(Q + (long)node * HID + cb * 128))[lane];
  float a0 = bf2f((unsigned short)(p & 0xFFFFu));
  float a1 = bf2f((unsigned short)(p >> 16));
  int e0 = rowptr[node], e1 = rowptr[node + 1];
  int j = e0;
  for (; j + 1 < e1; j += 2) {
    int s0 = csr[j], s1 = csr[j + 1];
    unsigned int q0 = ((const unsigned int*)(Q + (long)s0 * HID + cb * 128))[lane];
    unsigned int q1 = ((const unsigned int*)(Q + (long)s1 * HID + cb * 128))[lane];
    a0 += bf2f((unsigned short)(q0 & 0xFFFFu));
    a1 += bf2f((unsigned short)(q0 >> 16));
    a0 += bf2f((unsigned short)(q1 & 0xFFFFu));
    a1 += bf2f((unsigned short)(q1 >> 16));
  }
  if (j < e1) {
    int s = csr[j];
    unsigned int q = ((const unsigned int*)(Q + (long)s * HID + cb * 128))[lane];
    a0 += bf2f((unsigned short)(q & 0xFFFFu));
    a1 += bf2f((unsigned short)(q >> 16));
  }
  unsigned int o = (unsigned int)f2bf(a0) | ((unsigned int)f2bf(a1) << 16);
  ((unsigned int*)(out + (long)node * ostride))[lane] = o;
}

// Q[:, cb*128 : cb*128+128] = T  (uint4 = 8 bf16 per thread)
__global__ void copyback_cols(unsigned short* __restrict__ Q,
                              const unsigned short* __restrict__ T, int cb) {
  long i = (long)blockIdx.x * 256 + threadIdx.x;  // uint4 index
  if (i < (long)N_NODES * 16) {
    long node = i >> 4;
    int c = (int)(i & 15);
    ((uint4*)(Q + node * HID + cb * 128))[c] = ((const uint4*)T)[i];
  }
}

// ---------------------------------------------------------------------------
// GEMM: C[M,N] = A[M,K] @ Bt[N,K]^T + bias(bf16), optional relu.
// akoff: uniform logical->physical K rotation for A reads (power-of-2 K).
// EPI: 0=bf16 out, 1=bf16 relu out, 2=f32 out, 3=f32 fused log-softmax
//      (EPI==3 requires BN==64==N: each 16-lane segment holds a full row).
// NOTE: in-place C==A is UNSAFE when grid.y > 1 (sibling column-blocks read
// all K columns of the shared row-slab while another writes its slice).
// ---------------------------------------------------------------------------
template <int WGM, int WGN, int EPI>
__global__ __launch_bounds__(256, 2) void gemm_bt(
    const unsigned short* __restrict__ A, const unsigned short* __restrict__ Bt,
    const unsigned short* __restrict__ bias, void* __restrict__ Cout,
    int M, int N, int K, int akoff) {
  constexpr int BM = WGM * 64;
  constexpr int BN = WGN * 64;
  __shared__ alignas(16) unsigned short ldsA[BM * 64];
  __shared__ alignas(16) unsigned short ldsB[BN * 64];
  const int tid = threadIdx.x;
  const int lane = tid & 63;
  const int w = tid >> 6;
  const int wm = w % WGM;
  const int wn = w / WGM;
  const long row0 = (long)blockIdx.x * BM;
  const long col0 = (long)blockIdx.y * BN;
  const int l15 = lane & 15, lq = lane >> 4;

  f32x4 acc[4][4];
#pragma unroll
  for (int i = 0; i < 4; ++i)
#pragma unroll
    for (int j = 0; j < 4; ++j) acc[i][j] = f32x4{0.f, 0.f, 0.f, 0.f};

  for (int k0 = 0; k0 < K; k0 += 64) {
    const int ka = (k0 + akoff) & (K - 1);
#pragma unroll
    for (int i = 0; i < BM * 8 / 256; ++i) {
      int t = i * 256 + tid;
      int r = t >> 3, c = t & 7;
      long gr = row0 + r;
      if (gr >= M) gr = M - 1;
      const unsigned short* g = A + gr * (long)K + ka + ((c ^ (r & 7)) << 3);
      void* l = (char*)ldsA + (size_t)(i * 256 + (tid & ~63)) * 16;
      async16(g, l);
    }
#pragma unroll
    for (int i = 0; i < BN * 8 / 256; ++i) {
      int t = i * 256 + tid;
      int r = t >> 3, c = t & 7;
      long gr = col0 + r;
      const unsigned short* g = Bt + gr * (long)K + k0 + ((c ^ (r & 7)) << 3);
      void* l = (char*)ldsB + (size_t)(i * 256 + (tid & ~63)) * 16;
      async16(g, l);
    }
    __syncthreads();
#pragma unroll
    for (int kk = 0; kk < 64; kk += 32) {
      bf16x8 av[4], bv[4];
#pragma unroll
      for (int mt = 0; mt < 4; ++mt) {
        int m = wm * 64 + mt * 16 + l15;
        int jj = ((kk >> 3) + lq) ^ (m & 7);
        av[mt] = *(const bf16x8*)(ldsA + m * 64 + jj * 8);
      }
#pragma unroll
      for (int nt = 0; nt < 4; ++nt) {
        int n = wn * 64 + nt * 16 + l15;
        int jj = ((kk >> 3) + lq) ^ (n & 7);
        bv[nt] = *(const bf16x8*)(ldsB + n * 64 + jj * 8);
      }
#pragma unroll
      for (int mt = 0; mt < 4; ++mt)
#pragma unroll
        for (int nt = 0; nt < 4; ++nt)
          acc[mt][nt] = __builtin_amdgcn_mfma_f32_16x16x32_bf16(
              av[mt], bv[nt], acc[mt][nt], 0, 0, 0);
    }
    __syncthreads();
  }

  if (EPI == 3) {
    float bvx[4];
#pragma unroll
    for (int nt = 0; nt < 4; ++nt) bvx[nt] = bf2f(bias[wn * 64 + nt * 16 + l15]);
#pragma unroll
    for (int mt = 0; mt < 4; ++mt) {
#pragma unroll
      for (int r = 0; r < 4; ++r) {
        long gm = row0 + wm * 64 + mt * 16 + lq * 4 + r;
        float v[4];
#pragma unroll
        for (int nt = 0; nt < 4; ++nt) v[nt] = acc[mt][nt][r] + bvx[nt];
        float mx = fmaxf(fmaxf(v[0], v[1]), fmaxf(v[2], v[3]));
#pragma unroll
        for (int o = 1; o < 16; o <<= 1) mx = fmaxf(mx, __shfl_xor(mx, o, 16));
        float s = expf(v[0] - mx) + expf(v[1] - mx) + expf(v[2] - mx) + expf(v[3] - mx);
#pragma unroll
        for (int o = 1; o < 16; o <<= 1) s += __shfl_xor(s, o, 16);
        float ls = logf(s);
        if (gm < M) {
#pragma unroll
          for (int nt = 0; nt < 4; ++nt)
            ((float*)Cout)[gm * N + nt * 16 + l15] = v[nt] - mx - ls;
        }
      }
    }
    return;
  }

#pragma unroll
  for (int nt = 0; nt < 4; ++nt) {
    long gn = col0 + wn * 64 + nt * 16 + l15;
    float bvl = bf2f(bias[gn]);
#pragma unroll
    for (int mt = 0; mt < 4; ++mt) {
      long gm0 = row0 + wm * 64 + mt * 16 + lq * 4;
#pragma unroll
      for (int r = 0; r < 4; ++r) {
        long gm = gm0 + r;
        if (gm < M) {
          float v = acc[mt][nt][r] + bvl;
          if (EPI == 1) v = v > 0.f ? v : 0.f;
          if (EPI == 2)
            ((float*)Cout)[gm * N + gn] = v;
          else
            ((unsigned short*)Cout)[gm * N + gn] = f2bf(v);
        }
      }
    }
  }
}

extern "C" void kernel_launch(void* const* d_in, const int* in_sizes, int n_in,
                              void* d_out, int out_size, void* d_ws,
                              size_t ws_size, hipStream_t stream) {
  const void* x = d_in[0];
  const unsigned int* ei = (const unsigned int*)d_in[1];
  const void* W1a = d_in[2];
  const void* b1a = d_in[3];
  const void* W1b = d_in[4];
  const void* b1b = d_in[5];
  const void* W2a = d_in[6];
  const void* b2a = d_in[7];
  const void* W2b = d_in[8];
  const void* b2b = d_in[9];
  const void* Wfc = d_in[10];
  const void* bfc = d_in[11];
  (void)n_in; (void)in_sizes; (void)out_size;

  // ---- adaptive chunking (layer-1 only): big layout if workspace permits ----
  const size_t BIG_NEED = 246909600;
  const bool big = (ws_size >= BIG_NEED);
  const int CMr = big ? 16384 : 8192;
  const int NFULLr = big ? 6 : 12;
  const int TAILR = N_NODES - NFULLr * CMr;   // 1696 either way

  char* wsb = (char*)d_ws;
  const size_t HOFF = (size_t)N_NODES * (HID - D_IN);
  const size_t AGG_OFF = 204800000;
  const size_t W_OFFv = big ? 238354432 : 233600000;
  const size_t WBYTES = 6946816;
  const size_t B_OFFv = W_OFFv + WBYTES;
  const size_t RP_OFFv = B_OFFv + 8320;
  const size_t CSR_OFFv = RP_OFFv + 400016;
  const size_t F_OFFv = CSR_OFFv + 1200000;
  unsigned short* Q = (unsigned short*)(wsb + 0);
  unsigned short* hQ = Q + HOFF;
  unsigned short* T1 = (unsigned short*)(wsb + AGG_OFF);
  int* src32 = (int*)(wsb + AGG_OFF);            // setup-only, dies before T1 use
  int* dst32 = src32 + N_EDGES;
  int* deg = dst32 + N_EDGES;
  int* cursor = deg + N_NODES;
  int* bsum = (int*)(wsb + AGG_OFF + 4 * 1024 * 1024);  // setup-only (98 ints)
  // sub-region [AGG+25.6e6, AGG+27.84e6): W2bN (temp), WcombT, bcomb, zbias.
  // Live from the Wcomb build (post-layer1) through the head. Never touched by:
  // agg2 slice-0 buffer (exactly 25.6e6 B), 2a-chunk T1 (CH2*2048 <= 25.17e6 B).
  // Big-layout layer-1 T1 (33.5MB) overlaps but dies before the build.
  unsigned short* W2bN = (unsigned short*)(wsb + AGG_OFF + 25600000);       // 2MB temp
  unsigned short* WcombT = (unsigned short*)(wsb + AGG_OFF + 25600000 + 2097152);
  unsigned short* bcomb = WcombT + (size_t)N_CLASSES * HID;                 // 128B
  unsigned short* zbias = bcomb + 64;                                      // 2KB zeros
  unsigned short* W1aT = (unsigned short*)(wsb + W_OFFv);
  unsigned short* W1bT = W1aT + (size_t)D_IN * HID;
  unsigned short* W2aT = W1bT + (size_t)HID * HID;
  unsigned short* W2bT = W2aT + (size_t)HID * HID;
  unsigned short* WfcT = W2bT + (size_t)HID * HID;
  unsigned short* bb1a = (unsigned short*)(wsb + B_OFFv);
  unsigned short* bb1b = bb1a + HID;
  unsigned short* bb2a = bb1b + HID;
  unsigned short* bb2b = bb2a + HID;
  unsigned short* bbfc = bb2b + HID;
  int* rowptr = (int*)(wsb + RP_OFFv);
  int* csr = (int*)(wsb + CSR_OFFv);
  int* flags = (int*)(wsb + F_OFFv);

  // ---- setup: dtype probe, edge/weight normalization, CSR build ----
  probe_flags<<<1, 256, 0, stream>>>((const unsigned short*)W1a, ei, flags);
  cvt_edges<<<(N_EDGES + 255) / 256, 256, 0, stream>>>(ei, src32, dst32, flags);
  hipMemsetAsync(deg, 0, (size_t)N_NODES * 4, stream);
  hist_deg<<<(N_EDGES + 255) / 256, 256, 0, stream>>>(dst32, deg);
  scan_part<<<NSCAN, 1024, 0, stream>>>(deg, rowptr, bsum);
  scan_top<<<1, 128, 0, stream>>>(bsum);
  scan_fix<<<NSCAN, 1024, 0, stream>>>(deg, rowptr, cursor, bsum);
  fill_csr<<<(N_EDGES + 255) / 256, 256, 0, stream>>>(src32, dst32, cursor, csr);
  cvt_bias_all<<<(4 * HID + N_CLASSES + 255) / 256, 256, 0, stream>>>(
      b1a, b1b, b2a, b2b, bfc, bb1a, flags);
  transpose_tile<0><<<dim3(HID / 64, D_IN / 64), 256, 0, stream>>>(W1a, W1aT, D_IN, HID, flags);
  transpose_tile<0><<<dim3(HID / 64, HID / 64), 256, 0, stream>>>(W1b, W1bT, HID, HID, flags);
  transpose_tile<0><<<dim3(HID / 64, HID / 64), 256, 0, stream>>>(W2a, W2aT, HID, HID, flags);
  transpose_tile<0><<<dim3(HID / 64, HID / 64), 256, 0, stream>>>(W2b, W2bT, HID, HID, flags);
  transpose_tile<0><<<dim3(N_CLASSES / 64, HID / 64), 256, 0, stream>>>(Wfc, WfcT, HID, N_CLASSES, flags);

  const int ngrid = (N_NODES + 3) / 4;  // one wave per node, 4 waves/block

  // ---- layer 1 aggregation (atomic-free, one pass) ----
  agg1_full<<<ngrid, 256, 0, stream>>>(x, rowptr, csr, hQ, flags);

  // ---- layer 1 GEMMs, chunked through T1 ----
  for (int c = 0; c <= NFULLr; ++c) {
    int rows = (c < NFULLr) ? CMr : TAILR;
    if (rows <= 0) break;
    const unsigned short* Ac = hQ + (size_t)c * CMr * D_IN;
    unsigned short* Qc = Q + (size_t)c * CMr * HID;
    dim3 g((rows + 127) / 128, HID / 128);
    gemm_bt<2, 2, 1><<<g, 256, 0, stream>>>(Ac, W1aT, bb1a, T1, rows, HID, D_IN, 0);
    gemm_bt<2, 2, 1><<<g, 256, 0, stream>>>(T1, W1bT, bb1b, Qc, rows, HID, HID, 0);
  }

  // ---- build combined head weights: Wcomb = W2b @ Wfc, bcomb = b2b@Wfc+bfc
  // (valid: NO nonlinearity between conv2's second linear and the head:
  // logits = U@(W2b@Wfc) + (b2b@Wfc + bfc), U = relu(agg2@W2a+b2a)).
  hipMemsetAsync(zbias, 0, 2048, stream);
  transpose_tile<1><<<dim3(HID / 64, HID / 64), 256, 0, stream>>>(W2bT, W2bN, HID, HID, flags);
  // WcombT[c][k] = sum_j WfcT[c][j] * W2bN[k][j]   (M=64, N=1024, K=1024)
  gemm_bt<1, 4, 0><<<dim3(1, 4), 256, 0, stream>>>(WfcT, W2bN, zbias, WcombT, 64, HID, HID, 0);
  bcomb_kernel<<<1, 64, 0, stream>>>(bb2b, WfcT, bbfc, bcomb);

  // ---- layer 2 aggregation: rotated in-place column slices ----
  for (int cb = 0; cb < HID / 128; ++cb) {
    if (cb == 0)
      agg2_rot<<<ngrid, 256, 0, stream>>>(Q, rowptr, csr, T1, 128, 0);
    else
      agg2_rot<<<ngrid, 256, 0, stream>>>(Q, rowptr, csr,
                                          Q + (size_t)(cb - 1) * 128, HID, cb);
  }
  const int cgrid = (int)(((long)N_NODES * 16 + 255) / 256);
  copyback_cols<<<cgrid, 256, 0, stream>>>(Q, T1, 7);

  // ---- layer 2a (out-of-place via T1) + fused head+log-softmax, chunked ----
  // CH2*HID*2 = 25,165,824 B < 25.6e6 -> T1 never touches WcombT region.
  const int CH2 = 12288, NF2 = 8;
  for (int c = 0; c <= NF2; ++c) {
    int rows = (c < NF2) ? CH2 : (N_NODES - NF2 * CH2);   // tail 1696
    if (rows <= 0) break;
    unsigned short* Qc = Q + (size_t)c * CH2 * HID;
    dim3 g((rows + 127) / 128, HID / 128);
    gemm_bt<2, 2, 1><<<g, 256, 0, stream>>>(Qc, W2aT, bb2a, T1, rows, HID, HID, 896);
    dim3 gh((rows + 255) / 256, 1);
    gemm_bt<4, 1, 3><<<gh, 256, 0, stream>>>(
        T1, WcombT, bcomb, (float*)d_out + (size_t)c * CH2 * N_CLASSES,
        rows, N_CLASSES, HID, 0);
  }
}

// Round 9
// 1371.747 us; speedup vs baseline: 1.1478x; 1.1478x over previous
//
#include <hip/hip_runtime.h>
#include <stdint.h>

#define N_NODES 100000
#define N_EDGES 300000
#define D_IN 256
#define HID 1024
#define N_CLASSES 64
#define NSCAN ((N_NODES + 1023) / 1024)   // 98 scan blocks

typedef __bf16 bf16x8 __attribute__((ext_vector_type(8)));
typedef float f32x4 __attribute__((ext_vector_type(4)));

__device__ __forceinline__ float bf2f(unsigned short u) {
  union { unsigned int i; float f; } v; v.i = ((unsigned int)u) << 16; return v.f;
}
__device__ __forceinline__ unsigned short f2bf(float f) {
  union { float f; unsigned int i; } v; v.f = f;
  unsigned int u = v.i;
  unsigned int r = (u + 0x7FFFu + ((u >> 16) & 1u)) >> 16;  // RNE
  return (unsigned short)r;
}

// async global->LDS, 16B per lane; LDS dest wave-uniform base, 16B-aligned
__device__ __forceinline__ void async16(const void* g, void* l) {
  __builtin_amdgcn_global_load_lds(
      (const __attribute__((address_space(1))) void*)g,
      (__attribute__((address_space(3))) void*)l, 16, 0, 0);
}

// ---------------------------------------------------------------------------
// dtype probe: flags[0]=1 if float tensors are f32 (vs bf16),
//              flags[1]=1 if edge_index is int64 (vs int32).
// ---------------------------------------------------------------------------
__global__ void probe_flags(const unsigned short* __restrict__ w,
                            const unsigned int* __restrict__ e,
                            int* __restrict__ flags) {
  __shared__ int cnt;
  __shared__ unsigned int orv;
  if (threadIdx.x == 0) { cnt = 0; orv = 0u; }
  __syncthreads();
  int c = 0;
  for (int i = threadIdx.x; i < 4096; i += 256) {
    unsigned int ex = (w[i] >> 7) & 0xFFu;
    if (ex > 123u) ++c;
  }
  atomicAdd(&cnt, c);
  unsigned int o = 0;
  for (int j = threadIdx.x; j < 1000; j += 256) o |= e[2 * j + 1];
  atomicOr(&orv, o);
  __syncthreads();
  if (threadIdx.x == 0) {
    flags[0] = (cnt > 64) ? 1 : 0;
    flags[1] = (orv == 0u) ? 1 : 0;
  }
}

__global__ void cvt_edges(const unsigned int* __restrict__ ei,
                          int* __restrict__ src32, int* __restrict__ dst32,
                          const int* __restrict__ flags) {
  int i = blockIdx.x * 256 + threadIdx.x;
  if (i >= N_EDGES) return;
  if (flags[1]) {
    src32[i] = (int)ei[2 * i];
    dst32[i] = (int)ei[2 * (size_t)N_EDGES + 2 * i];
  } else {
    src32[i] = (int)ei[i];
    dst32[i] = (int)ei[N_EDGES + i];
  }
}

// LDS-tiled 64x64 transpose: coalesced read AND write.
// grid = (N/64, K/64). FB16=1 forces bf16 input (ignores flags).
template <int FB16>
__global__ void transpose_tile(const void* __restrict__ W,
                               unsigned short* __restrict__ Wt, int K, int N,
                               const int* __restrict__ flags) {
  __shared__ float t[64][65];   // +1 pad: LDS reads 2-way max (free)
  const int n0 = blockIdx.x * 64, k0 = blockIdx.y * 64;
  const int lane = threadIdx.x & 63, rg = threadIdx.x >> 6;
  const bool isf32 = FB16 ? false : (flags[0] != 0);
#pragma unroll
  for (int i = 0; i < 16; ++i) {
    int r = rg * 16 + i;
    long idx = (long)(k0 + r) * N + n0 + lane;
    t[r][lane] = isf32 ? ((const float*)W)[idx]
                       : bf2f(((const unsigned short*)W)[idx]);
  }
  __syncthreads();
#pragma unroll
  for (int i = 0; i < 16; ++i) {
    int r = rg * 16 + i;
    Wt[(long)(n0 + r) * K + k0 + lane] = f2bf(t[lane][r]);
  }
}

// all 5 biases in one launch; dst buffers are contiguous (bb1a..bbfc).
__global__ void cvt_bias_all(const void* __restrict__ b1a, const void* __restrict__ b1b,
                             const void* __restrict__ b2a, const void* __restrict__ b2b,
                             const void* __restrict__ bfc,
                             unsigned short* __restrict__ bb,
                             const int* __restrict__ flags) {
  int i = blockIdx.x * 256 + threadIdx.x;
  if (i >= 4 * HID + N_CLASSES) return;
  const void* src; int off;
  if (i < HID)          { src = b1a; off = i; }
  else if (i < 2 * HID) { src = b1b; off = i - HID; }
  else if (i < 3 * HID) { src = b2a; off = i - 2 * HID; }
  else if (i < 4 * HID) { src = b2b; off = i - 3 * HID; }
  else                  { src = bfc; off = i - 4 * HID; }
  bb[i] = flags[0] ? f2bf(((const float*)src)[off])
                   : ((const unsigned short*)src)[off];
}

// bcomb[c] = sum_j b2b[j] * Wfc[j][c] + bfc[c]   (f32 accum, bf16 out)
__global__ void bcomb_kernel(const unsigned short* __restrict__ bb2b,
                             const unsigned short* __restrict__ WfcT,
                             const unsigned short* __restrict__ bbfc,
                             unsigned short* __restrict__ bcomb) {
  int c = threadIdx.x;
  if (c >= N_CLASSES) return;
  float s = bf2f(bbfc[c]);
  for (int j = 0; j < HID; ++j)
    s += bf2f(bb2b[j]) * bf2f(WfcT[(long)c * HID + j]);
  bcomb[c] = f2bf(s);
}

// ---------------- CSR build (counting sort by dst) ----------------
__global__ void hist_deg(const int* __restrict__ dst, int* __restrict__ deg) {
  int e = blockIdx.x * 256 + threadIdx.x;
  if (e < N_EDGES) atomicAdd(&deg[dst[e]], 1);
}

__global__ void scan_part(const int* __restrict__ deg, int* __restrict__ rowptr,
                          int* __restrict__ bsum) {
  __shared__ int lds[1024];
  int i = blockIdx.x * 1024 + threadIdx.x;
  int v = (i < N_NODES) ? deg[i] : 0;
  lds[threadIdx.x] = v;
  __syncthreads();
  for (int off = 1; off < 1024; off <<= 1) {
    int t = (threadIdx.x >= off) ? lds[threadIdx.x - off] : 0;
    __syncthreads();
    lds[threadIdx.x] += t;
    __syncthreads();
  }
  if (i < N_NODES) rowptr[i + 1] = lds[threadIdx.x];
  if (threadIdx.x == 1023) bsum[blockIdx.x] = lds[1023];
}

__global__ void scan_top(int* __restrict__ bsum) {
  __shared__ int lds[128];
  int v = (threadIdx.x < NSCAN) ? bsum[threadIdx.x] : 0;
  lds[threadIdx.x] = v;
  __syncthreads();
  for (int off = 1; off < 128; off <<= 1) {
    int t = (threadIdx.x >= off) ? lds[threadIdx.x - off] : 0;
    __syncthreads();
    lds[threadIdx.x] += t;
    __syncthreads();
  }
  if (threadIdx.x < NSCAN) bsum[threadIdx.x] = lds[threadIdx.x] - v;  // exclusive
}

__global__ void scan_fix(const int* __restrict__ deg, int* __restrict__ rowptr,
                         int* __restrict__ cursor, const int* __restrict__ bsum) {
  int i = blockIdx.x * 1024 + threadIdx.x;
  if (i < N_NODES) {
    int incl = rowptr[i + 1] + bsum[blockIdx.x];
    rowptr[i + 1] = incl;
    cursor[i] = incl - deg[i];
  }
  if (i == 0) rowptr[0] = 0;
}

__global__ void fill_csr(const int* __restrict__ src, const int* __restrict__ dst,
                         int* __restrict__ cursor, int* __restrict__ csr) {
  int e = blockIdx.x * 256 + threadIdx.x;
  if (e < N_EDGES) {
    int pos = atomicAdd(&cursor[dst[e]], 1);
    csr[pos] = src[e];
  }
}

// ---- atomic-free aggregation, one wave per node ----
// layer 1: h[n] = bf16(x[n] + sum_j x[csr[j]])  (edge loop x4, order-preserving)
__global__ void agg1_full(const void* __restrict__ X,
                          const int* __restrict__ rowptr,
                          const int* __restrict__ csr,
                          unsigned short* __restrict__ h,
                          const int* __restrict__ flags) {
  int node = blockIdx.x * 4 + (threadIdx.x >> 6);
  int lane = threadIdx.x & 63;
  if (node >= N_NODES) return;
  bool isf32 = flags[0] != 0;
  float acc[4];
  int e0 = rowptr[node], e1 = rowptr[node + 1];
  if (isf32) {
    const float* Xf = (const float*)X;
    float4 v = ((const float4*)(Xf + (long)node * D_IN))[lane];
    acc[0] = v.x; acc[1] = v.y; acc[2] = v.z; acc[3] = v.w;
    int j = e0;
    for (; j + 3 < e1; j += 4) {
      int s0 = csr[j], s1 = csr[j + 1], s2 = csr[j + 2], s3 = csr[j + 3];
      float4 v0 = ((const float4*)(Xf + (long)s0 * D_IN))[lane];
      float4 v1 = ((const float4*)(Xf + (long)s1 * D_IN))[lane];
      float4 v2 = ((const float4*)(Xf + (long)s2 * D_IN))[lane];
      float4 v3 = ((const float4*)(Xf + (long)s3 * D_IN))[lane];
      acc[0] += v0.x; acc[1] += v0.y; acc[2] += v0.z; acc[3] += v0.w;
      acc[0] += v1.x; acc[1] += v1.y; acc[2] += v1.z; acc[3] += v1.w;
      acc[0] += v2.x; acc[1] += v2.y; acc[2] += v2.z; acc[3] += v2.w;
      acc[0] += v3.x; acc[1] += v3.y; acc[2] += v3.z; acc[3] += v3.w;
    }
    for (; j < e1; ++j) {
      int s = csr[j];
      float4 v0 = ((const float4*)(Xf + (long)s * D_IN))[lane];
      acc[0] += v0.x; acc[1] += v0.y; acc[2] += v0.z; acc[3] += v0.w;
    }
  } else {
    const unsigned short* Xb = (const unsigned short*)X;
    ushort4 v = ((const ushort4*)(Xb + (long)node * D_IN))[lane];
    acc[0] = bf2f(v.x); acc[1] = bf2f(v.y); acc[2] = bf2f(v.z); acc[3] = bf2f(v.w);
    int j = e0;
    for (; j + 3 < e1; j += 4) {
      int s0 = csr[j], s1 = csr[j + 1], s2 = csr[j + 2], s3 = csr[j + 3];
      ushort4 v0 = ((const ushort4*)(Xb + (long)s0 * D_IN))[lane];
      ushort4 v1 = ((const ushort4*)(Xb + (long)s1 * D_IN))[lane];
      ushort4 v2 = ((const ushort4*)(Xb + (long)s2 * D_IN))[lane];
      ushort4 v3 = ((const ushort4*)(Xb + (long)s3 * D_IN))[lane];
      acc[0] += bf2f(v0.x); acc[1] += bf2f(v0.y); acc[2] += bf2f(v0.z); acc[3] += bf2f(v0.w);
      acc[0] += bf2f(v1.x); acc[1] += bf2f(v1.y); acc[2] += bf2f(v1.z); acc[3] += bf2f(v1.w);
      acc[0] += bf2f(v2.x); acc[1] += bf2f(v2.y); acc[2] += bf2f(v2.z); acc[3] += bf2f(v2.w);
      acc[0] += bf2f(v3.x); acc[1] += bf2f(v3.y); acc[2] += bf2f(v3.z); acc[3] += bf2f(v3.w);
    }
    for (; j < e1; ++j) {
      int s = csr[j];
      ushort4 v0 = ((const ushort4*)(Xb + (long)s * D_IN))[lane];
      acc[0] += bf2f(v0.x); acc[1] += bf2f(v0.y); acc[2] += bf2f(v0.z); acc[3] += bf2f(v0.w);
    }
  }
  ushort4 o;
  o.x = f2bf(acc[0]); o.y = f2bf(acc[1]); o.z = f2bf(acc[2]); o.w = f2bf(acc[3]);
  ((ushort4*)(h + (long)node * D_IN))[lane] = o;
}

__device__ __forceinline__ void add8(float* a, unsigned int x, unsigned int y,
                                     unsigned int z, unsigned int w) {
  a[0] += bf2f((unsigned short)(x & 0xFFFFu)); a[1] += bf2f((unsigned short)(x >> 16));
  a[2] += bf2f((unsigned short)(y & 0xFFFFu)); a[3] += bf2f((unsigned short)(y >> 16));
  a[4] += bf2f((unsigned short)(z & 0xFFFFu)); a[5] += bf2f((unsigned short)(z >> 16));
  a[6] += bf2f((unsigned short)(w & 0xFFFFu)); a[7] += bf2f((unsigned short)(w >> 16));
}

// single-pass full-width layer-2 aggregation (huge tier): U = Q + A.Q
// one wave per node; 16 f32 accum/lane; 2KB-row gathers; edge order preserved.
__global__ void agg2_full(const unsigned short* __restrict__ Qin,
                          const int* __restrict__ rowptr,
                          const int* __restrict__ csr,
                          unsigned short* __restrict__ Uout) {
  int node = blockIdx.x * 4 + (threadIdx.x >> 6);
  int lane = threadIdx.x & 63;
  if (node >= N_NODES) return;
  float acc[16];
  {
    const uint4* row = (const uint4*)(Qin + (long)node * HID);
    uint4 a = row[lane], b = row[64 + lane];
    acc[0] = bf2f((unsigned short)(a.x & 0xFFFFu)); acc[1] = bf2f((unsigned short)(a.x >> 16));
    acc[2] = bf2f((unsigned short)(a.y & 0xFFFFu)); acc[3] = bf2f((unsigned short)(a.y >> 16));
    acc[4] = bf2f((unsigned short)(a.z & 0xFFFFu)); acc[5] = bf2f((unsigned short)(a.z >> 16));
    acc[6] = bf2f((unsigned short)(a.w & 0xFFFFu)); acc[7] = bf2f((unsigned short)(a.w >> 16));
    acc[8] = bf2f((unsigned short)(b.x & 0xFFFFu)); acc[9] = bf2f((unsigned short)(b.x >> 16));
    acc[10] = bf2f((unsigned short)(b.y & 0xFFFFu)); acc[11] = bf2f((unsigned short)(b.y >> 16));
    acc[12] = bf2f((unsigned short)(b.z & 0xFFFFu)); acc[13] = bf2f((unsigned short)(b.z >> 16));
    acc[14] = bf2f((unsigned short)(b.w & 0xFFFFu)); acc[15] = bf2f((unsigned short)(b.w >> 16));
  }
  int e0 = rowptr[node], e1 = rowptr[node + 1];
  int j = e0;
  for (; j + 1 < e1; j += 2) {
    const uint4* r0 = (const uint4*)(Qin + (long)csr[j] * HID);
    const uint4* r1 = (const uint4*)(Qin + (long)csr[j + 1] * HID);
    uint4 a0 = r0[lane], b0 = r0[64 + lane];
    uint4 a1 = r1[lane], b1 = r1[64 + lane];
    add8(acc, a0.x, a0.y, a0.z, a0.w);
    add8(acc + 8, b0.x, b0.y, b0.z, b0.w);
    add8(acc, a1.x, a1.y, a1.z, a1.w);
    add8(acc + 8, b1.x, b1.y, b1.z, b1.w);
  }
  if (j < e1) {
    const uint4* r0 = (const uint4*)(Qin + (long)csr[j] * HID);
    uint4 a0 = r0[lane], b0 = r0[64 + lane];
    add8(acc, a0.x, a0.y, a0.z, a0.w);
    add8(acc + 8, b0.x, b0.y, b0.z, b0.w);
  }
  uint4 oa, ob;
  oa.x = (unsigned)f2bf(acc[0]) | ((unsigned)f2bf(acc[1]) << 16);
  oa.y = (unsigned)f2bf(acc[2]) | ((unsigned)f2bf(acc[3]) << 16);
  oa.z = (unsigned)f2bf(acc[4]) | ((unsigned)f2bf(acc[5]) << 16);
  oa.w = (unsigned)f2bf(acc[6]) | ((unsigned)f2bf(acc[7]) << 16);
  ob.x = (unsigned)f2bf(acc[8]) | ((unsigned)f2bf(acc[9]) << 16);
  ob.y = (unsigned)f2bf(acc[10]) | ((unsigned)f2bf(acc[11]) << 16);
  ob.z = (unsigned)f2bf(acc[12]) | ((unsigned)f2bf(acc[13]) << 16);
  ob.w = (unsigned)f2bf(acc[14]) | ((unsigned)f2bf(acc[15]) << 16);
  uint4* orow = (uint4*)(Uout + (long)node * HID);
  orow[lane] = oa; orow[64 + lane] = ob;
}

// layer 2 aggregation, 128-col slice w/ column rotation (mid tier); x4 unroll.
__global__ void agg2_rot(const unsigned short* __restrict__ Q,
                         const int* __restrict__ rowptr,
                         const int* __restrict__ csr,
                         unsigned short* __restrict__ out, long ostride, int cb) {
  int node = blockIdx.x * 4 + (threadIdx.x >> 6);
  int lane = threadIdx.x & 63;
  if (node >= N_NODES) return;
  unsigned int p = ((const unsigned int*)(Q + (long)node * HID + cb * 128))[lane];
  float a0 = bf2f((unsigned short)(p & 0xFFFFu));
  float a1 = bf2f((unsigned short)(p >> 16));
  int e0 = rowptr[node], e1 = rowptr[node + 1];
  int j = e0;
  for (; j + 3 < e1; j += 4) {
    int s0 = csr[j], s1 = csr[j + 1], s2 = csr[j + 2], s3 = csr[j + 3];
    unsigned int q0 = ((const unsigned int*)(Q + (long)s0 * HID + cb * 128))[lane];
    unsigned int q1 = ((const unsigned int*)(Q + (long)s1 * HID + cb * 128))[lane];
    unsigned int q2 = ((const unsigned int*)(Q + (long)s2 * HID + cb * 128))[lane];
    unsigned int q3 = ((const unsigned int*)(Q + (long)s3 * HID + cb * 128))[lane];
    a0 += bf2f((unsigned short)(q0 & 0xFFFFu)); a1 += bf2f((unsigned short)(q0 >> 16));
    a0 += bf2f((unsigned short)(q1 & 0xFFFFu)); a1 += bf2f((unsigned short)(q1 >> 16));
    a0 += bf2f((unsigned short)(q2 & 0xFFFFu)); a1 += bf2f((unsigned short)(q2 >> 16));
    a0 += bf2f((unsigned short)(q3 & 0xFFFFu)); a1 += bf2f((unsigned short)(q3 >> 16));
  }
  for (; j < e1; ++j) {
    int s = csr[j];
    unsigned int q = ((const unsigned int*)(Q + (long)s * HID + cb * 128))[lane];
    a0 += bf2f((unsigned short)(q & 0xFFFFu)); a1 += bf2f((unsigned short)(q >> 16));
  }
  unsigned int o = (unsigned int)f2bf(a0) | ((unsigned int)f2bf(a1) << 16);
  ((unsigned int*)(out + (long)node * ostride))[lane] = o;
}

// Q[:, cb*128 : cb*128+128] = T  (uint4 = 8 bf16 per thread)
__global__ void copyback_cols(unsigned short* __restrict__ Q,
                              const unsigned short* __restrict__ T, int cb) {
  long i = (long)blockIdx.x * 256 + threadIdx.x;  // uint4 index
  if (i < (long)N_NODES * 16) {
    long node = i >> 4;
    int c = (int)(i & 15);
    ((uint4*)(Q + node * HID + cb * 128))[c] = ((const uint4*)T)[i];
  }
}

// ---------------------------------------------------------------------------
// GEMM: C[M,N] = A[M,K] @ Bt[N,K]^T + bias(bf16), optional relu.
// akoff: uniform logical->physical K rotation for A reads (power-of-2 K).
// EPI: 0=bf16 out, 1=bf16 relu out, 2=f32 out, 3=f32 fused log-softmax
//      (EPI==3 requires BN==64==N). In-place C==A is UNSAFE when grid.y > 1.
// ---------------------------------------------------------------------------
template <int WGM, int WGN, int EPI>
__global__ __launch_bounds__(256, 2) void gemm_bt(
    const unsigned short* __restrict__ A, const unsigned short* __restrict__ Bt,
    const unsigned short* __restrict__ bias, void* __restrict__ Cout,
    int M, int N, int K, int akoff) {
  constexpr int BM = WGM * 64;
  constexpr int BN = WGN * 64;
  __shared__ alignas(16) unsigned short ldsA[BM * 64];
  __shared__ alignas(16) unsigned short ldsB[BN * 64];
  const int tid = threadIdx.x;
  const int lane = tid & 63;
  const int w = tid >> 6;
  const int wm = w % WGM;
  const int wn = w / WGM;
  const long row0 = (long)blockIdx.x * BM;
  const long col0 = (long)blockIdx.y * BN;
  const int l15 = lane & 15, lq = lane >> 4;

  f32x4 acc[4][4];
#pragma unroll
  for (int i = 0; i < 4; ++i)
#pragma unroll
    for (int j = 0; j < 4; ++j) acc[i][j] = f32x4{0.f, 0.f, 0.f, 0.f};

  for (int k0 = 0; k0 < K; k0 += 64) {
    const int ka = (k0 + akoff) & (K - 1);
#pragma unroll
    for (int i = 0; i < BM * 8 / 256; ++i) {
      int t = i * 256 + tid;
      int r = t >> 3, c = t & 7;
      long gr = row0 + r;
      if (gr >= M) gr = M - 1;
      const unsigned short* g = A + gr * (long)K + ka + ((c ^ (r & 7)) << 3);
      void* l = (char*)ldsA + (size_t)(i * 256 + (tid & ~63)) * 16;
      async16(g, l);
    }
#pragma unroll
    for (int i = 0; i < BN * 8 / 256; ++i) {
      int t = i * 256 + tid;
      int r = t >> 3, c = t & 7;
      long gr = col0 + r;
      const unsigned short* g = Bt + gr * (long)K + k0 + ((c ^ (r & 7)) << 3);
      void* l = (char*)ldsB + (size_t)(i * 256 + (tid & ~63)) * 16;
      async16(g, l);
    }
    __syncthreads();
#pragma unroll
    for (int kk = 0; kk < 64; kk += 32) {
      bf16x8 av[4], bv[4];
#pragma unroll
      for (int mt = 0; mt < 4; ++mt) {
        int m = wm * 64 + mt * 16 + l15;
        int jj = ((kk >> 3) + lq) ^ (m & 7);
        av[mt] = *(const bf16x8*)(ldsA + m * 64 + jj * 8);
      }
#pragma unroll
      for (int nt = 0; nt < 4; ++nt) {
        int n = wn * 64 + nt * 16 + l15;
        int jj = ((kk >> 3) + lq) ^ (n & 7);
        bv[nt] = *(const bf16x8*)(ldsB + n * 64 + jj * 8);
      }
#pragma unroll
      for (int mt = 0; mt < 4; ++mt)
#pragma unroll
        for (int nt = 0; nt < 4; ++nt)
          acc[mt][nt] = __builtin_amdgcn_mfma_f32_16x16x32_bf16(
              av[mt], bv[nt], acc[mt][nt], 0, 0, 0);
    }
    __syncthreads();
  }

  if (EPI == 3) {
    float bvx[4];
#pragma unroll
    for (int nt = 0; nt < 4; ++nt) bvx[nt] = bf2f(bias[wn * 64 + nt * 16 + l15]);
#pragma unroll
    for (int mt = 0; mt < 4; ++mt) {
#pragma unroll
      for (int r = 0; r < 4; ++r) {
        long gm = row0 + wm * 64 + mt * 16 + lq * 4 + r;
        float v[4];
#pragma unroll
        for (int nt = 0; nt < 4; ++nt) v[nt] = acc[mt][nt][r] + bvx[nt];
        float mx = fmaxf(fmaxf(v[0], v[1]), fmaxf(v[2], v[3]));
#pragma unroll
        for (int o = 1; o < 16; o <<= 1) mx = fmaxf(mx, __shfl_xor(mx, o, 16));
        float s = expf(v[0] - mx) + expf(v[1] - mx) + expf(v[2] - mx) + expf(v[3] - mx);
#pragma unroll
        for (int o = 1; o < 16; o <<= 1) s += __shfl_xor(s, o, 16);
        float ls = logf(s);
        if (gm < M) {
#pragma unroll
          for (int nt = 0; nt < 4; ++nt)
            ((float*)Cout)[gm * N + nt * 16 + l15] = v[nt] - mx - ls;
        }
      }
    }
    return;
  }

#pragma unroll
  for (int nt = 0; nt < 4; ++nt) {
    long gn = col0 + wn * 64 + nt * 16 + l15;
    float bvl = bf2f(bias[gn]);
#pragma unroll
    for (int mt = 0; mt < 4; ++mt) {
      long gm0 = row0 + wm * 64 + mt * 16 + lq * 4;
#pragma unroll
      for (int r = 0; r < 4; ++r) {
        long gm = gm0 + r;
        if (gm < M) {
          float v = acc[mt][nt][r] + bvl;
          if (EPI == 1) v = v > 0.f ? v : 0.f;
          if (EPI == 2)
            ((float*)Cout)[gm * N + gn] = v;
          else
            ((unsigned short*)Cout)[gm * N + gn] = f2bf(v);
        }
      }
    }
  }
}

extern "C" void kernel_launch(void* const* d_in, const int* in_sizes, int n_in,
                              void* d_out, int out_size, void* d_ws,
                              size_t ws_size, hipStream_t stream) {
  const void* x = d_in[0];
  const unsigned int* ei = (const unsigned int*)d_in[1];
  const void* W1a = d_in[2];
  const void* b1a = d_in[3];
  const void* W1b = d_in[4];
  const void* b1b = d_in[5];
  const void* W2a = d_in[6];
  const void* b2a = d_in[7];
  const void* W2b = d_in[8];
  const void* b2b = d_in[9];
  const void* Wfc = d_in[10];
  const void* bfc = d_in[11];
  (void)n_in; (void)in_sizes; (void)out_size;

  char* wsb = (char*)d_ws;
  const size_t HOFF = (size_t)N_NODES * (HID - D_IN);
  const size_t HUGE_NEED = 420385568;   // Q + full U ping-pong + tails
  const size_t BIG_NEED = 246909600;

  if (ws_size >= HUGE_NEED) {
    // =========== HUGE tier: two full buffers, zero chunking/rotation ========
    // Q [0,204.8M) ; U [204.8M,409.6M) ; weights/bias/comb/CSR tail after.
    const size_t U_OFF = 204800000;
    const size_t W_OFF3 = 409600000;
    unsigned short* Q = (unsigned short*)(wsb + 0);
    unsigned short* hQ = Q + HOFF;
    unsigned short* U = (unsigned short*)(wsb + U_OFF);
    int* src32 = (int*)(wsb + U_OFF);          // setup-only, dead before U use
    int* dst32 = src32 + N_EDGES;
    int* deg = dst32 + N_EDGES;
    int* cursor = deg + N_NODES;
    int* bsum = (int*)(wsb + U_OFF + 4 * 1024 * 1024);
    unsigned short* W1aT = (unsigned short*)(wsb + W_OFF3);
    unsigned short* W1bT = W1aT + (size_t)D_IN * HID;
    unsigned short* W2aT = W1bT + (size_t)HID * HID;
    unsigned short* W2bT = W2aT + (size_t)HID * HID;
    unsigned short* WfcT = W2bT + (size_t)HID * HID;
    unsigned short* bb1a = WfcT + (size_t)HID * N_CLASSES;
    unsigned short* bb1b = bb1a + HID;
    unsigned short* bb2a = bb1b + HID;
    unsigned short* bb2b = bb2a + HID;
    unsigned short* bbfc = bb2b + HID;
    unsigned short* W2bN = bbfc + N_CLASSES;                  // 2MB temp
    unsigned short* WcombT = W2bN + (size_t)HID * HID;
    unsigned short* bcomb = WcombT + (size_t)N_CLASSES * HID;
    unsigned short* zbias = bcomb + 64;
    int* rowptr = (int*)(zbias + 1024);
    int* csr = rowptr + N_NODES + 4;
    int* flags = csr + N_EDGES;

    probe_flags<<<1, 256, 0, stream>>>((const unsigned short*)W1a, ei, flags);
    cvt_edges<<<(N_EDGES + 255) / 256, 256, 0, stream>>>(ei, src32, dst32, flags);
    hipMemsetAsync(deg, 0, (size_t)N_NODES * 4, stream);
    hist_deg<<<(N_EDGES + 255) / 256, 256, 0, stream>>>(dst32, deg);
    scan_part<<<NSCAN, 1024, 0, stream>>>(deg, rowptr, bsum);
    scan_top<<<1, 128, 0, stream>>>(bsum);
    scan_fix<<<NSCAN, 1024, 0, stream>>>(deg, rowptr, cursor, bsum);
    fill_csr<<<(N_EDGES + 255) / 256, 256, 0, stream>>>(src32, dst32, cursor, csr);
    cvt_bias_all<<<(4 * HID + N_CLASSES + 255) / 256, 256, 0, stream>>>(
        b1a, b1b, b2a, b2b, bfc, bb1a, flags);
    transpose_tile<0><<<dim3(HID / 64, D_IN / 64), 256, 0, stream>>>(W1a, W1aT, D_IN, HID, flags);
    transpose_tile<0><<<dim3(HID / 64, HID / 64), 256, 0, stream>>>(W1b, W1bT, HID, HID, flags);
    transpose_tile<0><<<dim3(HID / 64, HID / 64), 256, 0, stream>>>(W2a, W2aT, HID, HID, flags);
    transpose_tile<0><<<dim3(HID / 64, HID / 64), 256, 0, stream>>>(W2b, W2bT, HID, HID, flags);
    transpose_tile<0><<<dim3(N_CLASSES / 64, HID / 64), 256, 0, stream>>>(Wfc, WfcT, HID, N_CLASSES, flags);
    // combined head weights (no nonlinearity between conv2-lin-b and head):
    hipMemsetAsync(zbias, 0, 2048, stream);
    transpose_tile<1><<<dim3(HID / 64, HID / 64), 256, 0, stream>>>(W2bT, W2bN, HID, HID, flags);
    gemm_bt<1, 4, 0><<<dim3(1, 4), 256, 0, stream>>>(WfcT, W2bN, zbias, WcombT, 64, HID, HID, 0);
    bcomb_kernel<<<1, 64, 0, stream>>>(bb2b, WfcT, bbfc, bcomb);

    const int ngrid = (N_NODES + 3) / 4;
    agg1_full<<<ngrid, 256, 0, stream>>>(x, rowptr, csr, hQ, flags);  // -> hQ
    dim3 gfull((N_NODES + 127) / 128, HID / 128);
    // layer 1: hQ -> U -> Q (setup arrays in U are dead now)
    gemm_bt<2, 2, 1><<<gfull, 256, 0, stream>>>(hQ, W1aT, bb1a, U, N_NODES, HID, D_IN, 0);
    gemm_bt<2, 2, 1><<<gfull, 256, 0, stream>>>(U, W1bT, bb1b, Q, N_NODES, HID, HID, 0);
    // layer 2: single-pass full-width aggregation Q -> U
    agg2_full<<<ngrid, 256, 0, stream>>>(Q, rowptr, csr, U);
    // 2a: U -> Q (natural layout, akoff=0)
    gemm_bt<2, 2, 1><<<gfull, 256, 0, stream>>>(U, W2aT, bb2a, Q, N_NODES, HID, HID, 0);
    // fused (conv2-lin-b + head) + log-softmax: one full-M dispatch
    dim3 ghead((N_NODES + 255) / 256, 1);
    gemm_bt<4, 1, 3><<<ghead, 256, 0, stream>>>(
        Q, WcombT, bcomb, (float*)d_out, N_NODES, N_CLASSES, HID, 0);
    return;
  }

  // ============== MID/SMALL tier (round-8 structure + head fix) =============
  const bool big = (ws_size >= BIG_NEED);
  const int CMr = big ? 16384 : 8192;
  const int NFULLr = big ? 6 : 12;
  const int TAILR = N_NODES - NFULLr * CMr;   // 1696 either way

  const size_t AGG_OFF = 204800000;
  const size_t W_OFFv = big ? 238354432 : 233600000;
  const size_t WBYTES = 6946816;
  const size_t B_OFFv = W_OFFv + WBYTES;
  const size_t RP_OFFv = B_OFFv + 8320;
  const size_t CSR_OFFv = RP_OFFv + 400016;
  const size_t F_OFFv = CSR_OFFv + 1200000;
  unsigned short* Q = (unsigned short*)(wsb + 0);
  unsigned short* hQ = Q + HOFF;
  unsigned short* T1 = (unsigned short*)(wsb + AGG_OFF);
  int* src32 = (int*)(wsb + AGG_OFF);
  int* dst32 = src32 + N_EDGES;
  int* deg = dst32 + N_EDGES;
  int* cursor = deg + N_NODES;
  int* bsum = (int*)(wsb + AGG_OFF + 4 * 1024 * 1024);
  unsigned short* W2bN = (unsigned short*)(wsb + AGG_OFF + 25600000);
  unsigned short* WcombT = (unsigned short*)(wsb + AGG_OFF + 25600000 + 2097152);
  unsigned short* bcomb = WcombT + (size_t)N_CLASSES * HID;
  unsigned short* zbias = bcomb + 64;
  unsigned short* W1aT = (unsigned short*)(wsb + W_OFFv);
  unsigned short* W1bT = W1aT + (size_t)D_IN * HID;
  unsigned short* W2aT = W1bT + (size_t)HID * HID;
  unsigned short* W2bT = W2aT + (size_t)HID * HID;
  unsigned short* WfcT = W2bT + (size_t)HID * HID;
  unsigned short* bb1a = (unsigned short*)(wsb + B_OFFv);
  unsigned short* bb1b = bb1a + HID;
  unsigned short* bb2a = bb1b + HID;
  unsigned short* bb2b = bb2a + HID;
  unsigned short* bbfc = bb2b + HID;
  int* rowptr = (int*)(wsb + RP_OFFv);
  int* csr = (int*)(wsb + CSR_OFFv);
  int* flags = (int*)(wsb + F_OFFv);

  probe_flags<<<1, 256, 0, stream>>>((const unsigned short*)W1a, ei, flags);
  cvt_edges<<<(N_EDGES + 255) / 256, 256, 0, stream>>>(ei, src32, dst32, flags);
  hipMemsetAsync(deg, 0, (size_t)N_NODES * 4, stream);
  hist_deg<<<(N_EDGES + 255) / 256, 256, 0, stream>>>(dst32, deg);
  scan_part<<<NSCAN, 1024, 0, stream>>>(deg, rowptr, bsum);
  scan_top<<<1, 128, 0, stream>>>(bsum);
  scan_fix<<<NSCAN, 1024, 0, stream>>>(deg, rowptr, cursor, bsum);
  fill_csr<<<(N_EDGES + 255) / 256, 256, 0, stream>>>(src32, dst32, cursor, csr);
  cvt_bias_all<<<(4 * HID + N_CLASSES + 255) / 256, 256, 0, stream>>>(
      b1a, b1b, b2a, b2b, bfc, bb1a, flags);
  transpose_tile<0><<<dim3(HID / 64, D_IN / 64), 256, 0, stream>>>(W1a, W1aT, D_IN, HID, flags);
  transpose_tile<0><<<dim3(HID / 64, HID / 64), 256, 0, stream>>>(W1b, W1bT, HID, HID, flags);
  transpose_tile<0><<<dim3(HID / 64, HID / 64), 256, 0, stream>>>(W2a, W2aT, HID, HID, flags);
  transpose_tile<0><<<dim3(HID / 64, HID / 64), 256, 0, stream>>>(W2b, W2bT, HID, HID, flags);
  transpose_tile<0><<<dim3(N_CLASSES / 64, HID / 64), 256, 0, stream>>>(Wfc, WfcT, HID, N_CLASSES, flags);

  const int ngrid = (N_NODES + 3) / 4;
  agg1_full<<<ngrid, 256, 0, stream>>>(x, rowptr, csr, hQ, flags);

  for (int c = 0; c <= NFULLr; ++c) {
    int rows = (c < NFULLr) ? CMr : TAILR;
    if (rows <= 0) break;
    const unsigned short* Ac = hQ + (size_t)c * CMr * D_IN;
    unsigned short* Qc = Q + (size_t)c * CMr * HID;
    dim3 g((rows + 127) / 128, HID / 128);
    gemm_bt<2, 2, 1><<<g, 256, 0, stream>>>(Ac, W1aT, bb1a, T1, rows, HID, D_IN, 0);
    gemm_bt<2, 2, 1><<<g, 256, 0, stream>>>(T1, W1bT, bb1b, Qc, rows, HID, HID, 0);
  }

  hipMemsetAsync(zbias, 0, 2048, stream);
  transpose_tile<1><<<dim3(HID / 64, HID / 64), 256, 0, stream>>>(W2bT, W2bN, HID, HID, flags);
  gemm_bt<1, 4, 0><<<dim3(1, 4), 256, 0, stream>>>(WfcT, W2bN, zbias, WcombT, 64, HID, HID, 0);
  bcomb_kernel<<<1, 64, 0, stream>>>(bb2b, WfcT, bbfc, bcomb);

  for (int cb = 0; cb < HID / 128; ++cb) {
    if (cb == 0)
      agg2_rot<<<ngrid, 256, 0, stream>>>(Q, rowptr, csr, T1, 128, 0);
    else
      agg2_rot<<<ngrid, 256, 0, stream>>>(Q, rowptr, csr,
                                          Q + (size_t)(cb - 1) * 128, HID, cb);
  }
  const int cgrid = (int)(((long)N_NODES * 16 + 255) / 256);
  copyback_cols<<<cgrid, 256, 0, stream>>>(Q, T1, 7);

  // layer-2a rotate-by-chunk: 2a(c) reads Q slot c, writes slot c-1 (dead);
  // c=0 -> T1. U then lives contiguously: rows [0,CH2) in T1, rest at Q+0.
  const int CH2 = 12288, NF2 = 8;
  for (int c = 0; c <= NF2; ++c) {
    int rows = (c < NF2) ? CH2 : (N_NODES - NF2 * CH2);   // tail 1696
    if (rows <= 0) break;
    unsigned short* Qc = Q + (size_t)c * CH2 * HID;
    unsigned short* out = (c == 0) ? T1 : Q + (size_t)(c - 1) * CH2 * HID;
    dim3 g((rows + 127) / 128, HID / 128);
    gemm_bt<2, 2, 1><<<g, 256, 0, stream>>>(Qc, W2aT, bb2a, out, rows, HID, HID, 896);
  }
  // heads: 2 dispatches over the two contiguous U pieces
  dim3 gh1((CH2 + 255) / 256, 1);
  gemm_bt<4, 1, 3><<<gh1, 256, 0, stream>>>(
      T1, WcombT, bcomb, (float*)d_out, CH2, N_CLASSES, HID, 0);
  const int rem = N_NODES - CH2;   // 87712
  dim3 gh2((rem + 255) / 256, 1);
  gemm_bt<4, 1, 3><<<gh2, 256, 0, stream>>>(
      Q, WcombT, bcomb, (float*)d_out + (size_t)CH2 * N_CLASSES,
      rem, N_CLASSES, HID, 0);
}